// Round 3
// baseline (285.223 us; speedup 1.0000x reference)
//
#include <hip/hip_runtime.h>
#include <hip/hip_bf16.h>

#define B 4096
#define DFEAT 128
#define NCLS 512
#define NEG_INF_F (-1e30f)

typedef __attribute__((ext_vector_type(8))) short bf16x8;
typedef __attribute__((ext_vector_type(4))) float f32x4;
typedef __attribute__((ext_vector_type(4))) int i32x4;

__device__ __forceinline__ unsigned short f2bf(float f) {
    unsigned int u = __float_as_uint(f);
    unsigned int r = (u + 0x7fffu + ((u >> 16) & 1u)) >> 16;
    return (unsigned short)r;
}

// online softmax-weighted accumulation: add one entry with given logit, value d
__device__ __forceinline__ void oupd(float logit, float d, float& m, float& sw, float& swd) {
    if (logit > m) {
        float e = __expf(m - logit);   // m==-1e30 -> e==0 -> resets cleanly
        sw  = fmaf(sw, e, 1.0f);
        swd = fmaf(swd, e, d);
        m = logit;
    } else {
        float e = __expf(logit - m);
        sw += e;
        swd = fmaf(e, d, swd);
    }
}

__device__ __forceinline__ void omerge(float& m, float& sw, float& swd,
                                       float m2, float sw2, float swd2) {
    float M = fmaxf(m, m2);
    float e1 = __expf(m - M);
    float e2 = __expf(m2 - M);
    sw  = sw * e1 + sw2 * e2;
    swd = swd * e1 + swd2 * e2;
    m = M;
}

// reference band logic for a strictly-upper negative pair
__device__ __forceinline__ void neg_update(float d, float mu, float sg, float nz, float st[12]) {
    float obs = fmaf(sg, nz, mu);
    float t1 = fmaf(-2.5f, sg, obs);
    if (d < t1) {
        oupd(10.0f * (t1 - d), d, st[0], st[1], st[2]);
    } else {
        float tm = fmaf(-1.5f, sg, obs);
        if (d < tm) {
            if (d > t1) oupd(5.0f * (tm - d), d, st[3], st[4], st[5]);
        } else {
            float th = fmaf(1.5f, sg, obs);
            if (d < th && d > tm) oupd(5.0f * (th - d), d, st[6], st[7], st[8]);
        }
    }
}

__device__ __forceinline__ void wave_reduce12(float st[12]) {
    #pragma unroll
    for (int off = 32; off; off >>= 1) {
        float o[12];
        #pragma unroll
        for (int k = 0; k < 12; ++k) o[k] = __shfl_down(st[k], off);
        omerge(st[0], st[1], st[2], o[0], o[1], o[2]);
        omerge(st[3], st[4], st[5], o[3], o[4], o[5]);
        omerge(st[6], st[7], st[8], o[6], o[7], o[8]);
        st[9] += o[9]; st[10] += o[10]; st[11] += o[11];
    }
}

// ---------------- kernel 1: x -> bf16 copy + row sum-of-squares ----------------
__global__ void prep_kernel(const float* __restrict__ x,
                            unsigned int* __restrict__ xbf_packed,
                            float* __restrict__ sq) {
    int row = blockIdx.x;
    int lane = threadIdx.x;  // 64
    float2 v = ((const float2*)(x + row * DFEAT))[lane];
    float ss = fmaf(v.x, v.x, v.y * v.y);
    unsigned int pk = ((unsigned int)f2bf(v.y) << 16) | (unsigned int)f2bf(v.x);
    xbf_packed[row * (DFEAT / 2) + lane] = pk;
    #pragma unroll
    for (int off = 32; off; off >>= 1) ss += __shfl_down(ss, off);
    if (lane == 0) sq[row] = ss;
}

// ---------------- kernel 1b: interleave (mean,std) -> float2 table ----------------
__global__ void pack_table_kernel(const float* __restrict__ meant,
                                  const float* __restrict__ stdt,
                                  float4* __restrict__ ms) {
    int i = blockIdx.x * 256 + threadIdx.x;   // handles 2 table entries
    float2 mu = ((const float2*)meant)[i];
    float2 sg = ((const float2*)stdt)[i];
    float4 o; o.x = mu.x; o.y = sg.x; o.z = mu.y; o.w = sg.y;
    ms[i] = o;
}

// ---------------- kernel 2: dist tile + balanced masked partial reductions ----------------
__launch_bounds__(256, 4)
__global__ void dist_loss_kernel(const unsigned short* __restrict__ xbf,
                                 const float* __restrict__ sq,
                                 const int* __restrict__ y,
                                 const float2* __restrict__ ms,
                                 const float* __restrict__ noise,
                                 float* __restrict__ out,
                                 float* __restrict__ partials) {
    const int bx = blockIdx.x;       // col tile
    const int by = blockIdx.y;       // row tile
    const int bid = by * 32 + bx;
    const int tid = threadIdx.x;
    const int wave = tid >> 6;
    const int lane = tid & 63;
    const int q = lane >> 4;         // 0..3
    const int l16 = lane & 15;
    const int row0 = by * 128 + (wave >> 1) * 64;
    const int col0 = bx * 128 + (wave & 1) * 64;

    f32x4 acc[4][4];
    #pragma unroll
    for (int r = 0; r < 4; ++r)
        #pragma unroll
        for (int c = 0; c < 4; ++c)
            acc[r][c] = (f32x4){0.f, 0.f, 0.f, 0.f};

    #pragma unroll
    for (int kk = 0; kk < 4; ++kk) {
        const int ko = kk * 32 + q * 8;
        bf16x8 afr[4], bfr[4];
        #pragma unroll
        for (int r = 0; r < 4; ++r)
            afr[r] = *(const bf16x8*)(xbf + (row0 + r * 16 + l16) * DFEAT + ko);
        #pragma unroll
        for (int c = 0; c < 4; ++c)
            bfr[c] = *(const bf16x8*)(xbf + (col0 + c * 16 + l16) * DFEAT + ko);
        #pragma unroll
        for (int r = 0; r < 4; ++r)
            #pragma unroll
            for (int c = 0; c < 4; ++c)
                acc[r][c] = __builtin_amdgcn_mfma_f32_16x16x32_bf16(afr[r], bfr[c], acc[r][c], 0, 0, 0);
    }

    // per-thread metadata
    f32x4 sqr4[4]; i32x4 yr4[4];
    #pragma unroll
    for (int r = 0; r < 4; ++r) {
        sqr4[r] = *(const f32x4*)(sq + row0 + r * 16 + q * 4);
        yr4[r]  = *(const i32x4*)(y  + row0 + r * 16 + q * 4);
    }
    int cols[4]; float sqc[4]; int yc[4];
    #pragma unroll
    for (int c = 0; c < 4; ++c) {
        cols[c] = col0 + c * 16 + l16;
        sqc[c] = sq[cols[c]];
        yc[c]  = y[cols[c]];
    }

    // full dist tile write (all blocks)
    #pragma unroll
    for (int r = 0; r < 4; ++r) {
        #pragma unroll
        for (int t = 0; t < 4; ++t) {
            int base = (row0 + r * 16 + q * 4 + t) * B;
            float s = sqr4[r][t];
            #pragma unroll
            for (int c = 0; c < 4; ++c)
                out[base + cols[c]] = fmaf(-2.0f, acc[r][c][t], s + sqc[c]);
        }
    }

    // st: [0..2]=n1(m,sw,swd) [3..5]=n2 [6..8]=n3 [9..11]=(ps,ps2,cnt)
    float st[12];
    st[0] = st[3] = st[6] = NEG_INF_F;
    st[1] = st[2] = st[4] = st[5] = st[7] = st[8] = st[9] = st[10] = st[11] = 0.f;

    if (bx > by) {
        // strict upper block: direct orientation, fragments with (r+c) even.
        // col>row always; positives impossible (rows/cols in different 128-tiles).
        #pragma unroll
        for (int r = 0; r < 4; ++r)
            #pragma unroll
            for (int c = 0; c < 4; ++c)
                if (((r + c) & 1) == 0) {
                    #pragma unroll
                    for (int t = 0; t < 4; ++t) {
                        int row = row0 + r * 16 + q * 4 + t;
                        float d = fmaf(-2.0f, acc[r][c][t], sqr4[r][t] + sqc[c]);
                        float nz = noise[(size_t)row * B + cols[c]];
                        float2 m2 = ms[yr4[r][t] * NCLS + yc[c]];
                        neg_update(d, m2.x, m2.y, nz, st);
                    }
                }
    } else if (bx < by) {
        // strict lower block: epilogue the MIRROR upper elements (transposed),
        // fragments with (r+c) odd. noise reads become contiguous float4.
        #pragma unroll
        for (int r = 0; r < 4; ++r)
            #pragma unroll
            for (int c = 0; c < 4; ++c)
                if (((r + c) & 1) == 1) {
                    f32x4 nz4 = *(const f32x4*)(noise + (size_t)cols[c] * B + row0 + r * 16 + q * 4);
                    #pragma unroll
                    for (int t = 0; t < 4; ++t) {
                        float d = fmaf(-2.0f, acc[r][c][t], sqr4[r][t] + sqc[c]);
                        float2 m2 = ms[yc[c] * NCLS + yr4[r][t]];
                        neg_update(d, m2.x, m2.y, nz4[t], st);
                    }
                }
    } else {
        // diagonal block: own strict-upper elements, frags with c>=r, pos+neg
        #pragma unroll
        for (int r = 0; r < 4; ++r)
            #pragma unroll
            for (int c = 0; c < 4; ++c)
                if (c >= r) {
                    #pragma unroll
                    for (int t = 0; t < 4; ++t) {
                        int row = row0 + r * 16 + q * 4 + t;
                        int col = cols[c];
                        if (col > row) {
                            float d = fmaf(-2.0f, acc[r][c][t], sqr4[r][t] + sqc[c]);
                            float nz = noise[(size_t)row * B + col];
                            float2 m2 = ms[yr4[r][t] * NCLS + yc[c]];
                            if ((row >> 3) == (col >> 3)) {
                                float obs = fmaf(m2.y, nz, m2.x);
                                float tp = fmaf(2.0f, m2.y, obs);
                                if (d > tp) {
                                    st[9] += d; st[10] = fmaf(d, d, st[10]); st[11] += 1.0f;
                                }
                            } else {
                                neg_update(d, m2.x, m2.y, nz, st);
                            }
                        }
                    }
                }
    }

    wave_reduce12(st);

    __shared__ float red[4][12];
    if (lane == 0) {
        #pragma unroll
        for (int k = 0; k < 12; ++k) red[wave][k] = st[k];
    }
    __syncthreads();
    if (tid == 0) {
        float r0[12];
        #pragma unroll
        for (int k = 0; k < 12; ++k) r0[k] = red[0][k];
        #pragma unroll
        for (int w = 1; w < 4; ++w) {
            omerge(r0[0], r0[1], r0[2], red[w][0], red[w][1], red[w][2]);
            omerge(r0[3], r0[4], r0[5], red[w][3], red[w][4], red[w][5]);
            omerge(r0[6], r0[7], r0[8], red[w][6], red[w][7], red[w][8]);
            r0[9] += red[w][9]; r0[10] += red[w][10]; r0[11] += red[w][11];
        }
        float* pp = partials + bid * 12;
        #pragma unroll
        for (int k = 0; k < 12; ++k) pp[k] = r0[k];
    }
}

// ---------------- kernel 3: final reduction + loss ----------------
__global__ void finalize_kernel(const float* __restrict__ partials,
                                float* __restrict__ out) {
    int tid = threadIdx.x;  // 256
    int lane = tid & 63, wave = tid >> 6;
    float st[12];
    st[0] = st[3] = st[6] = NEG_INF_F;
    st[1] = st[2] = st[4] = st[5] = st[7] = st[8] = st[9] = st[10] = st[11] = 0.f;
    for (int p = tid; p < 1024; p += 256) {
        const float* pp = partials + p * 12;
        omerge(st[0], st[1], st[2], pp[0], pp[1], pp[2]);
        omerge(st[3], st[4], st[5], pp[3], pp[4], pp[5]);
        omerge(st[6], st[7], st[8], pp[6], pp[7], pp[8]);
        st[9] += pp[9]; st[10] += pp[10]; st[11] += pp[11];
    }
    wave_reduce12(st);
    __shared__ float red[4][12];
    if (lane == 0) {
        #pragma unroll
        for (int k = 0; k < 12; ++k) red[wave][k] = st[k];
    }
    __syncthreads();
    if (tid == 0) {
        float r0[12];
        #pragma unroll
        for (int k = 0; k < 12; ++k) r0[k] = red[0][k];
        #pragma unroll
        for (int w = 1; w < 4; ++w) {
            omerge(r0[0], r0[1], r0[2], red[w][0], red[w][1], red[w][2]);
            omerge(r0[3], r0[4], r0[5], red[w][3], red[w][4], red[w][5]);
            omerge(r0[6], r0[7], r0[8], red[w][6], red[w][7], red[w][8]);
            r0[9] += red[w][9]; r0[10] += red[w][10]; r0[11] += red[w][11];
        }
        float ln1 = (r0[1] > 0.f) ? -(r0[2] / r0[1]) : -0.0001f;
        float ln2 = (r0[4] > 0.f) ? -(r0[5] / r0[4]) : -0.0001f;
        float ln3 = (r0[7] > 0.f) ? -(r0[8] / r0[7]) : -0.0001f;
        float lp  = (r0[11] > 0.f) ? (r0[10] / ((r0[9] != 0.f) ? r0[9] : 1.f)) : 0.0001f;
        out[(size_t)B * B] = 1.0f + 0.25f * (ln1 + ln2 + ln3 + lp);
    }
}

extern "C" void kernel_launch(void* const* d_in, const int* in_sizes, int n_in,
                              void* d_out, int out_size, void* d_ws, size_t ws_size,
                              hipStream_t stream) {
    const float* x     = (const float*)d_in[0];
    const int*   y     = (const int*)d_in[1];
    const float* meant = (const float*)d_in[2];
    const float* stdt  = (const float*)d_in[3];
    const float* noise = (const float*)d_in[4];
    float* out = (float*)d_out;
    char* ws = (char*)d_ws;
    unsigned short* xbf = (unsigned short*)ws;            // 1 MiB
    float* sq           = (float*)(ws + 1048576);         // 16 KiB
    float* partials     = (float*)(ws + 1064960);         // 48 KiB
    float2* ms          = (float2*)(ws + 2097152);        // 2 MiB (512*512*8B)

    hipLaunchKernelGGL(prep_kernel, dim3(B), dim3(64), 0, stream,
                       x, (unsigned int*)xbf, sq);
    hipLaunchKernelGGL(pack_table_kernel, dim3(NCLS * NCLS / 512), dim3(256), 0, stream,
                       meant, stdt, (float4*)ms);
    hipLaunchKernelGGL(dist_loss_kernel, dim3(32, 32), dim3(256), 0, stream,
                       xbf, sq, y, ms, noise, out, partials);
    hipLaunchKernelGGL(finalize_kernel, dim3(1), dim3(256), 0, stream,
                       partials, out);
}

// Round 4
// 249.367 us; speedup vs baseline: 1.1438x; 1.1438x over previous
//
#include <hip/hip_runtime.h>
#include <hip/hip_bf16.h>

#define B 4096
#define DFEAT 128
#define NCLS 512
#define NEG_INF_F (-1e30f)

typedef __attribute__((ext_vector_type(8))) short bf16x8;
typedef __attribute__((ext_vector_type(4))) float f32x4;
typedef __attribute__((ext_vector_type(4))) int i32x4;

__device__ __forceinline__ unsigned short f2bf(float f) {
    unsigned int u = __float_as_uint(f);
    unsigned int r = (u + 0x7fffu + ((u >> 16) & 1u)) >> 16;
    return (unsigned short)r;
}

// online softmax-weighted accumulation: add one entry with given logit, value d
__device__ __forceinline__ void oupd(float logit, float d, float& m, float& sw, float& swd) {
    if (logit > m) {
        float e = __expf(m - logit);   // m==-1e30 -> e==0 -> resets cleanly
        sw  = fmaf(sw, e, 1.0f);
        swd = fmaf(swd, e, d);
        m = logit;
    } else {
        float e = __expf(logit - m);
        sw += e;
        swd = fmaf(e, d, swd);
    }
}

__device__ __forceinline__ void omerge(float& m, float& sw, float& swd,
                                       float m2, float sw2, float swd2) {
    float M = fmaxf(m, m2);
    float e1 = __expf(m - M);
    float e2 = __expf(m2 - M);
    sw  = sw * e1 + sw2 * e2;
    swd = swd * e1 + swd2 * e2;
    m = M;
}

// reference band logic for a strictly-upper negative pair
__device__ __forceinline__ void neg_update(float d, float mu, float sg, float nz, float st[12]) {
    float obs = fmaf(sg, nz, mu);
    float t1 = fmaf(-2.5f, sg, obs);
    if (d < t1) {
        oupd(10.0f * (t1 - d), d, st[0], st[1], st[2]);
    } else {
        float tm = fmaf(-1.5f, sg, obs);
        if (d < tm) {
            if (d > t1) oupd(5.0f * (tm - d), d, st[3], st[4], st[5]);
        } else {
            float th = fmaf(1.5f, sg, obs);
            if (d < th && d > tm) oupd(5.0f * (th - d), d, st[6], st[7], st[8]);
        }
    }
}

__device__ __forceinline__ void wave_reduce12(float st[12]) {
    #pragma unroll
    for (int off = 32; off; off >>= 1) {
        float o[12];
        #pragma unroll
        for (int k = 0; k < 12; ++k) o[k] = __shfl_down(st[k], off);
        omerge(st[0], st[1], st[2], o[0], o[1], o[2]);
        omerge(st[3], st[4], st[5], o[3], o[4], o[5]);
        omerge(st[6], st[7], st[8], o[6], o[7], o[8]);
        st[9] += o[9]; st[10] += o[10]; st[11] += o[11];
    }
}

// ---------------- kernel 1: x -> bf16 copy + row sum-of-squares ----------------
__global__ void prep_kernel(const float* __restrict__ x,
                            unsigned int* __restrict__ xbf_packed,
                            float* __restrict__ sq) {
    int row = blockIdx.x;
    int lane = threadIdx.x;  // 64
    float2 v = ((const float2*)(x + row * DFEAT))[lane];
    float ss = fmaf(v.x, v.x, v.y * v.y);
    unsigned int pk = ((unsigned int)f2bf(v.y) << 16) | (unsigned int)f2bf(v.x);
    xbf_packed[row * (DFEAT / 2) + lane] = pk;
    #pragma unroll
    for (int off = 32; off; off >>= 1) ss += __shfl_down(ss, off);
    if (lane == 0) sq[row] = ss;
}

// ---------------- kernel 1b: interleave (mean,std) -> float2 table ----------------
__global__ void pack_table_kernel(const float* __restrict__ meant,
                                  const float* __restrict__ stdt,
                                  float4* __restrict__ ms) {
    int i = blockIdx.x * 256 + threadIdx.x;   // handles 2 table entries
    float2 mu = ((const float2*)meant)[i];
    float2 sg = ((const float2*)stdt)[i];
    float4 o; o.x = mu.x; o.y = sg.x; o.z = mu.y; o.w = sg.y;
    ms[i] = o;
}

// ---------------- kernel 2: dist tile + balanced masked partial reductions ----------------
__launch_bounds__(256)
__global__ void dist_loss_kernel(const unsigned short* __restrict__ xbf,
                                 const float* __restrict__ sq,
                                 const int* __restrict__ y,
                                 const float2* __restrict__ ms,
                                 const float* __restrict__ noise,
                                 float* __restrict__ out,
                                 float* __restrict__ partials) {
    const int bx = blockIdx.x;       // col tile
    const int by = blockIdx.y;       // row tile
    const int bid = by * 32 + bx;
    const int tid = threadIdx.x;
    const int wave = tid >> 6;
    const int lane = tid & 63;
    const int q = lane >> 4;         // 0..3
    const int l16 = lane & 15;
    const int row0 = by * 128 + (wave >> 1) * 64;
    const int col0 = bx * 128 + (wave & 1) * 64;

    f32x4 acc[4][4];
    #pragma unroll
    for (int r = 0; r < 4; ++r)
        #pragma unroll
        for (int c = 0; c < 4; ++c)
            acc[r][c] = (f32x4){0.f, 0.f, 0.f, 0.f};

    #pragma unroll
    for (int kk = 0; kk < 4; ++kk) {
        const int ko = kk * 32 + q * 8;
        bf16x8 afr[4], bfr[4];
        #pragma unroll
        for (int r = 0; r < 4; ++r)
            afr[r] = *(const bf16x8*)(xbf + (row0 + r * 16 + l16) * DFEAT + ko);
        #pragma unroll
        for (int c = 0; c < 4; ++c)
            bfr[c] = *(const bf16x8*)(xbf + (col0 + c * 16 + l16) * DFEAT + ko);
        #pragma unroll
        for (int r = 0; r < 4; ++r)
            #pragma unroll
            for (int c = 0; c < 4; ++c)
                acc[r][c] = __builtin_amdgcn_mfma_f32_16x16x32_bf16(afr[r], bfr[c], acc[r][c], 0, 0, 0);
    }

    // per-thread metadata
    f32x4 sqr4[4]; i32x4 yr4[4];
    #pragma unroll
    for (int r = 0; r < 4; ++r) {
        sqr4[r] = *(const f32x4*)(sq + row0 + r * 16 + q * 4);
        yr4[r]  = *(const i32x4*)(y  + row0 + r * 16 + q * 4);
    }
    int cols[4]; float sqc[4]; int yc[4];
    #pragma unroll
    for (int c = 0; c < 4; ++c) {
        cols[c] = col0 + c * 16 + l16;
        sqc[c] = sq[cols[c]];
        yc[c]  = y[cols[c]];
    }

    // full dist tile write (all blocks)
    #pragma unroll
    for (int r = 0; r < 4; ++r) {
        #pragma unroll
        for (int t = 0; t < 4; ++t) {
            int base = (row0 + r * 16 + q * 4 + t) * B;
            float s = sqr4[r][t];
            #pragma unroll
            for (int c = 0; c < 4; ++c)
                out[base + cols[c]] = fmaf(-2.0f, acc[r][c][t], s + sqc[c]);
        }
    }

    // st: [0..2]=n1(m,sw,swd) [3..5]=n2 [6..8]=n3 [9..11]=(ps,ps2,cnt)
    float st[12];
    st[0] = st[3] = st[6] = NEG_INF_F;
    st[1] = st[2] = st[4] = st[5] = st[7] = st[8] = st[9] = st[10] = st[11] = 0.f;

    if (bx > by) {
        // strict upper block: process OWN fragments r in {0,1}, all c.
        // noise reads row-major: per row the 4 c-stores span 256B, fully used.
        #pragma unroll
        for (int r = 0; r < 2; ++r) {
            #pragma unroll
            for (int t = 0; t < 4; ++t) {
                int row = row0 + r * 16 + q * 4 + t;
                float sqr = sqr4[r][t];
                int yi = yr4[r][t];
                const float* nrow = noise + (size_t)row * B;
                #pragma unroll
                for (int c = 0; c < 4; ++c) {
                    float d = fmaf(-2.0f, acc[r][c][t], sqr + sqc[c]);
                    float nz = nrow[cols[c]];
                    float2 m2 = ms[yi * NCLS + yc[c]];
                    neg_update(d, m2.x, m2.y, nz, st);
                }
            }
        }
    } else if (bx < by) {
        // strict lower block: process MIRROR of fragments c in {2,3}, all r
        // (transposed). These are exactly the upper elements the mirror block
        // skips. noise rows = cols[c]; per row the 4 r-reads span 256B, fully used.
        #pragma unroll
        for (int c = 2; c < 4; ++c) {
            const float* nrow = noise + (size_t)cols[c] * B + row0;
            int yj = yc[c];
            float sc = sqc[c];
            #pragma unroll
            for (int r = 0; r < 4; ++r) {
                f32x4 nz4 = *(const f32x4*)(nrow + r * 16 + q * 4);
                #pragma unroll
                for (int t = 0; t < 4; ++t) {
                    float d = fmaf(-2.0f, acc[r][c][t], sqr4[r][t] + sc);
                    float2 m2 = ms[yj * NCLS + yr4[r][t]];
                    neg_update(d, m2.x, m2.y, nz4[t], st);
                }
            }
        }
    } else {
        // diagonal block: own strict-upper elements, frags with c>=r, pos+neg
        #pragma unroll
        for (int r = 0; r < 4; ++r)
            #pragma unroll
            for (int c = 0; c < 4; ++c)
                if (c >= r) {
                    #pragma unroll
                    for (int t = 0; t < 4; ++t) {
                        int row = row0 + r * 16 + q * 4 + t;
                        int col = cols[c];
                        if (col > row) {
                            float d = fmaf(-2.0f, acc[r][c][t], sqr4[r][t] + sqc[c]);
                            float nz = noise[(size_t)row * B + col];
                            float2 m2 = ms[yr4[r][t] * NCLS + yc[c]];
                            if ((row >> 3) == (col >> 3)) {
                                float obs = fmaf(m2.y, nz, m2.x);
                                float tp = fmaf(2.0f, m2.y, obs);
                                if (d > tp) {
                                    st[9] += d; st[10] = fmaf(d, d, st[10]); st[11] += 1.0f;
                                }
                            } else {
                                neg_update(d, m2.x, m2.y, nz, st);
                            }
                        }
                    }
                }
    }

    wave_reduce12(st);

    __shared__ float red[4][12];
    if (lane == 0) {
        #pragma unroll
        for (int k = 0; k < 12; ++k) red[wave][k] = st[k];
    }
    __syncthreads();
    if (tid == 0) {
        float r0[12];
        #pragma unroll
        for (int k = 0; k < 12; ++k) r0[k] = red[0][k];
        #pragma unroll
        for (int w = 1; w < 4; ++w) {
            omerge(r0[0], r0[1], r0[2], red[w][0], red[w][1], red[w][2]);
            omerge(r0[3], r0[4], r0[5], red[w][3], red[w][4], red[w][5]);
            omerge(r0[6], r0[7], r0[8], red[w][6], red[w][7], red[w][8]);
            r0[9] += red[w][9]; r0[10] += red[w][10]; r0[11] += red[w][11];
        }
        float* pp = partials + bid * 12;
        #pragma unroll
        for (int k = 0; k < 12; ++k) pp[k] = r0[k];
    }
}

// ---------------- kernel 3: final reduction + loss ----------------
__global__ void finalize_kernel(const float* __restrict__ partials,
                                float* __restrict__ out) {
    int tid = threadIdx.x;  // 256
    int lane = tid & 63, wave = tid >> 6;
    float st[12];
    st[0] = st[3] = st[6] = NEG_INF_F;
    st[1] = st[2] = st[4] = st[5] = st[7] = st[8] = st[9] = st[10] = st[11] = 0.f;
    for (int p = tid; p < 1024; p += 256) {
        const float* pp = partials + p * 12;
        omerge(st[0], st[1], st[2], pp[0], pp[1], pp[2]);
        omerge(st[3], st[4], st[5], pp[3], pp[4], pp[5]);
        omerge(st[6], st[7], st[8], pp[6], pp[7], pp[8]);
        st[9] += pp[9]; st[10] += pp[10]; st[11] += pp[11];
    }
    wave_reduce12(st);
    __shared__ float red[4][12];
    if (lane == 0) {
        #pragma unroll
        for (int k = 0; k < 12; ++k) red[wave][k] = st[k];
    }
    __syncthreads();
    if (tid == 0) {
        float r0[12];
        #pragma unroll
        for (int k = 0; k < 12; ++k) r0[k] = red[0][k];
        #pragma unroll
        for (int w = 1; w < 4; ++w) {
            omerge(r0[0], r0[1], r0[2], red[w][0], red[w][1], red[w][2]);
            omerge(r0[3], r0[4], r0[5], red[w][3], red[w][4], red[w][5]);
            omerge(r0[6], r0[7], r0[8], red[w][6], red[w][7], red[w][8]);
            r0[9] += red[w][9]; r0[10] += red[w][10]; r0[11] += red[w][11];
        }
        float ln1 = (r0[1] > 0.f) ? -(r0[2] / r0[1]) : -0.0001f;
        float ln2 = (r0[4] > 0.f) ? -(r0[5] / r0[4]) : -0.0001f;
        float ln3 = (r0[7] > 0.f) ? -(r0[8] / r0[7]) : -0.0001f;
        float lp  = (r0[11] > 0.f) ? (r0[10] / ((r0[9] != 0.f) ? r0[9] : 1.f)) : 0.0001f;
        out[(size_t)B * B] = 1.0f + 0.25f * (ln1 + ln2 + ln3 + lp);
    }
}

extern "C" void kernel_launch(void* const* d_in, const int* in_sizes, int n_in,
                              void* d_out, int out_size, void* d_ws, size_t ws_size,
                              hipStream_t stream) {
    const float* x     = (const float*)d_in[0];
    const int*   y     = (const int*)d_in[1];
    const float* meant = (const float*)d_in[2];
    const float* stdt  = (const float*)d_in[3];
    const float* noise = (const float*)d_in[4];
    float* out = (float*)d_out;
    char* ws = (char*)d_ws;
    unsigned short* xbf = (unsigned short*)ws;            // 1 MiB
    float* sq           = (float*)(ws + 1048576);         // 16 KiB
    float* partials     = (float*)(ws + 1064960);         // 48 KiB
    float2* ms          = (float2*)(ws + 2097152);        // 2 MiB (512*512*8B)

    hipLaunchKernelGGL(prep_kernel, dim3(B), dim3(64), 0, stream,
                       x, (unsigned int*)xbf, sq);
    hipLaunchKernelGGL(pack_table_kernel, dim3(NCLS * NCLS / 512), dim3(256), 0, stream,
                       meant, stdt, (float4*)ms);
    hipLaunchKernelGGL(dist_loss_kernel, dim3(32, 32), dim3(256), 0, stream,
                       xbf, sq, y, ms, noise, out, partials);
    hipLaunchKernelGGL(finalize_kernel, dim3(1), dim3(256), 0, stream,
                       partials, out);
}

// Round 5
// 162.399 us; speedup vs baseline: 1.7563x; 1.5355x over previous
//
#include <hip/hip_runtime.h>
#include <hip/hip_bf16.h>

#define B 4096
#define DFEAT 128
#define NCLS 512
#define NEG_INF_F (-1e30f)

typedef __attribute__((ext_vector_type(8))) short bf16x8;
typedef __attribute__((ext_vector_type(4))) float f32x4;

__device__ __forceinline__ unsigned short f2bf(float f) {
    unsigned int u = __float_as_uint(f);
    unsigned int r = (u + 0x7fffu + ((u >> 16) & 1u)) >> 16;
    return (unsigned short)r;
}

// online softmax-weighted accumulation: add one entry with given logit, value d
__device__ __forceinline__ void oupd(float logit, float d, float& m, float& sw, float& swd) {
    if (logit > m) {
        float e = __expf(m - logit);   // m==-1e30 -> e==0 -> resets cleanly
        sw  = fmaf(sw, e, 1.0f);
        swd = fmaf(swd, e, d);
        m = logit;
    } else {
        float e = __expf(logit - m);
        sw += e;
        swd = fmaf(e, d, swd);
    }
}

__device__ __forceinline__ void omerge(float& m, float& sw, float& swd,
                                       float m2, float sw2, float swd2) {
    float M = fmaxf(m, m2);
    float e1 = __expf(m - M);
    float e2 = __expf(m2 - M);
    sw  = sw * e1 + sw2 * e2;
    swd = swd * e1 + swd2 * e2;
    m = M;
}

// reference band logic for a strictly-upper negative pair
__device__ __forceinline__ void neg_update(float d, float mu, float sg, float nz, float st[12]) {
    float obs = fmaf(sg, nz, mu);
    float t1 = fmaf(-2.5f, sg, obs);
    if (d < t1) {
        oupd(10.0f * (t1 - d), d, st[0], st[1], st[2]);
    } else {
        float tm = fmaf(-1.5f, sg, obs);
        if (d < tm) {
            if (d > t1) oupd(5.0f * (tm - d), d, st[3], st[4], st[5]);
        } else {
            float th = fmaf(1.5f, sg, obs);
            if (d < th && d > tm) oupd(5.0f * (th - d), d, st[6], st[7], st[8]);
        }
    }
}

__device__ __forceinline__ void wave_reduce12(float st[12]) {
    #pragma unroll
    for (int off = 32; off; off >>= 1) {
        float o[12];
        #pragma unroll
        for (int k = 0; k < 12; ++k) o[k] = __shfl_down(st[k], off);
        omerge(st[0], st[1], st[2], o[0], o[1], o[2]);
        omerge(st[3], st[4], st[5], o[3], o[4], o[5]);
        omerge(st[6], st[7], st[8], o[6], o[7], o[8]);
        st[9] += o[9]; st[10] += o[10]; st[11] += o[11];
    }
}

// ---------------- kernel 1: x -> bf16 copy + row sum-of-squares ----------------
__global__ void prep_kernel(const float* __restrict__ x,
                            unsigned int* __restrict__ xbf_packed,
                            float* __restrict__ sq) {
    int row = blockIdx.x;
    int lane = threadIdx.x;  // 64
    float2 v = ((const float2*)(x + row * DFEAT))[lane];
    float ss = fmaf(v.x, v.x, v.y * v.y);
    unsigned int pk = ((unsigned int)f2bf(v.y) << 16) | (unsigned int)f2bf(v.x);
    xbf_packed[row * (DFEAT / 2) + lane] = pk;
    #pragma unroll
    for (int off = 32; off; off >>= 1) ss += __shfl_down(ss, off);
    if (lane == 0) sq[row] = ss;
}

// ---------------- kernel 2: pure GEMM -> dist write ----------------
__launch_bounds__(256)
__global__ void dist_kernel(const unsigned short* __restrict__ xbf,
                            const float* __restrict__ sq,
                            float* __restrict__ out) {
    const int bx = blockIdx.x;       // col tile
    const int by = blockIdx.y;       // row tile
    const int tid = threadIdx.x;
    const int wave = tid >> 6;
    const int lane = tid & 63;
    const int q = lane >> 4;         // 0..3
    const int l16 = lane & 15;
    const int row0 = by * 128 + (wave >> 1) * 64;
    const int col0 = bx * 128 + (wave & 1) * 64;

    f32x4 acc[4][4];
    #pragma unroll
    for (int r = 0; r < 4; ++r)
        #pragma unroll
        for (int c = 0; c < 4; ++c)
            acc[r][c] = (f32x4){0.f, 0.f, 0.f, 0.f};

    #pragma unroll
    for (int kk = 0; kk < 4; ++kk) {
        const int ko = kk * 32 + q * 8;
        bf16x8 afr[4], bfr[4];
        #pragma unroll
        for (int r = 0; r < 4; ++r)
            afr[r] = *(const bf16x8*)(xbf + (row0 + r * 16 + l16) * DFEAT + ko);
        #pragma unroll
        for (int c = 0; c < 4; ++c)
            bfr[c] = *(const bf16x8*)(xbf + (col0 + c * 16 + l16) * DFEAT + ko);
        #pragma unroll
        for (int r = 0; r < 4; ++r)
            #pragma unroll
            for (int c = 0; c < 4; ++c)
                acc[r][c] = __builtin_amdgcn_mfma_f32_16x16x32_bf16(afr[r], bfr[c], acc[r][c], 0, 0, 0);
    }

    float sqr[4][4];
    #pragma unroll
    for (int r = 0; r < 4; ++r)
        *(f32x4*)sqr[r] = *(const f32x4*)(sq + row0 + r * 16 + q * 4);
    int cols[4]; float sqc[4];
    #pragma unroll
    for (int c = 0; c < 4; ++c) {
        cols[c] = col0 + c * 16 + l16;
        sqc[c] = sq[cols[c]];
    }

    #pragma unroll
    for (int r = 0; r < 4; ++r) {
        #pragma unroll
        for (int t = 0; t < 4; ++t) {
            int base = (row0 + r * 16 + q * 4 + t) * B;
            float s = sqr[r][t];
            #pragma unroll
            for (int c = 0; c < 4; ++c)
                out[base + cols[c]] = fmaf(-2.0f, acc[r][c][t], s + sqc[c]);
        }
    }
}

// ---------------- kernel 3: streaming upper-triangle loss ----------------
// block b handles rows i=b and j=B-1-b: exactly 4095 elements per block.
__launch_bounds__(256)
__global__ void loss_kernel(const float* __restrict__ dist,
                            const float* __restrict__ noise,
                            const int* __restrict__ y,
                            const float* __restrict__ meant,
                            const float* __restrict__ stdt,
                            float* __restrict__ partials) {
    const int b = blockIdx.x;       // 0..2047
    const int i = b;
    const int j = B - 1 - b;
    const int tid = threadIdx.x;
    const int lane = tid & 63, wave = tid >> 6;

    __shared__ float mu0[NCLS], sg0[NCLS], mu1[NCLS], sg1[NCLS];
    const int yi = y[i], yj = y[j];
    for (int c = tid; c < NCLS; c += 256) {
        mu0[c] = meant[yi * NCLS + c];
        sg0[c] = stdt[yi * NCLS + c];
        mu1[c] = meant[yj * NCLS + c];
        sg1[c] = stdt[yj * NCLS + c];
    }
    __syncthreads();

    // st: [0..2]=n1(m,sw,swd) [3..5]=n2 [6..8]=n3 [9..11]=(ps,ps2,cnt)
    float st[12];
    st[0] = st[3] = st[6] = NEG_INF_F;
    st[1] = st[2] = st[4] = st[5] = st[7] = st[8] = st[9] = st[10] = st[11] = 0.f;

    {   // row i
        const float* drow = dist + (size_t)i * B;
        const float* nrow = noise + (size_t)i * B;
        const int grp = i >> 3;
        for (int col = i + 1 + tid; col < B; col += 256) {
            float d  = drow[col];
            float nz = nrow[col];
            int yc = y[col];
            float mu = mu0[yc], sg = sg0[yc];
            if ((col >> 3) == grp) {
                float obs = fmaf(sg, nz, mu);
                float tp = fmaf(2.0f, sg, obs);
                if (d > tp) { st[9] += d; st[10] = fmaf(d, d, st[10]); st[11] += 1.0f; }
            } else {
                neg_update(d, mu, sg, nz, st);
            }
        }
    }
    {   // row j
        const float* drow = dist + (size_t)j * B;
        const float* nrow = noise + (size_t)j * B;
        const int grp = j >> 3;
        for (int col = j + 1 + tid; col < B; col += 256) {
            float d  = drow[col];
            float nz = nrow[col];
            int yc = y[col];
            float mu = mu1[yc], sg = sg1[yc];
            if ((col >> 3) == grp) {
                float obs = fmaf(sg, nz, mu);
                float tp = fmaf(2.0f, sg, obs);
                if (d > tp) { st[9] += d; st[10] = fmaf(d, d, st[10]); st[11] += 1.0f; }
            } else {
                neg_update(d, mu, sg, nz, st);
            }
        }
    }

    wave_reduce12(st);

    __shared__ float red[4][12];
    if (lane == 0) {
        #pragma unroll
        for (int k = 0; k < 12; ++k) red[wave][k] = st[k];
    }
    __syncthreads();
    if (tid == 0) {
        float r0[12];
        #pragma unroll
        for (int k = 0; k < 12; ++k) r0[k] = red[0][k];
        #pragma unroll
        for (int w = 1; w < 4; ++w) {
            omerge(r0[0], r0[1], r0[2], red[w][0], red[w][1], red[w][2]);
            omerge(r0[3], r0[4], r0[5], red[w][3], red[w][4], red[w][5]);
            omerge(r0[6], r0[7], r0[8], red[w][6], red[w][7], red[w][8]);
            r0[9] += red[w][9]; r0[10] += red[w][10]; r0[11] += red[w][11];
        }
        float* pp = partials + b * 12;
        #pragma unroll
        for (int k = 0; k < 12; ++k) pp[k] = r0[k];
    }
}

// ---------------- kernel 4: final reduction + loss ----------------
__global__ void finalize_kernel(const float* __restrict__ partials,
                                float* __restrict__ out) {
    int tid = threadIdx.x;  // 256
    int lane = tid & 63, wave = tid >> 6;
    float st[12];
    st[0] = st[3] = st[6] = NEG_INF_F;
    st[1] = st[2] = st[4] = st[5] = st[7] = st[8] = st[9] = st[10] = st[11] = 0.f;
    for (int p = tid; p < 2048; p += 256) {
        const float* pp = partials + p * 12;
        omerge(st[0], st[1], st[2], pp[0], pp[1], pp[2]);
        omerge(st[3], st[4], st[5], pp[3], pp[4], pp[5]);
        omerge(st[6], st[7], st[8], pp[6], pp[7], pp[8]);
        st[9] += pp[9]; st[10] += pp[10]; st[11] += pp[11];
    }
    wave_reduce12(st);
    __shared__ float red[4][12];
    if (lane == 0) {
        #pragma unroll
        for (int k = 0; k < 12; ++k) red[wave][k] = st[k];
    }
    __syncthreads();
    if (tid == 0) {
        float r0[12];
        #pragma unroll
        for (int k = 0; k < 12; ++k) r0[k] = red[0][k];
        #pragma unroll
        for (int w = 1; w < 4; ++w) {
            omerge(r0[0], r0[1], r0[2], red[w][0], red[w][1], red[w][2]);
            omerge(r0[3], r0[4], r0[5], red[w][3], red[w][4], red[w][5]);
            omerge(r0[6], r0[7], r0[8], red[w][6], red[w][7], red[w][8]);
            r0[9] += red[w][9]; r0[10] += red[w][10]; r0[11] += red[w][11];
        }
        float ln1 = (r0[1] > 0.f) ? -(r0[2] / r0[1]) : -0.0001f;
        float ln2 = (r0[4] > 0.f) ? -(r0[5] / r0[4]) : -0.0001f;
        float ln3 = (r0[7] > 0.f) ? -(r0[8] / r0[7]) : -0.0001f;
        float lp  = (r0[11] > 0.f) ? (r0[10] / ((r0[9] != 0.f) ? r0[9] : 1.f)) : 0.0001f;
        out[(size_t)B * B] = 1.0f + 0.25f * (ln1 + ln2 + ln3 + lp);
    }
}

extern "C" void kernel_launch(void* const* d_in, const int* in_sizes, int n_in,
                              void* d_out, int out_size, void* d_ws, size_t ws_size,
                              hipStream_t stream) {
    const float* x     = (const float*)d_in[0];
    const int*   y     = (const int*)d_in[1];
    const float* meant = (const float*)d_in[2];
    const float* stdt  = (const float*)d_in[3];
    const float* noise = (const float*)d_in[4];
    float* out = (float*)d_out;
    char* ws = (char*)d_ws;
    unsigned short* xbf = (unsigned short*)ws;            // 1 MiB
    float* sq           = (float*)(ws + 1048576);         // 16 KiB
    float* partials     = (float*)(ws + 1064960);         // 2048*12*4 = 96 KiB

    hipLaunchKernelGGL(prep_kernel, dim3(B), dim3(64), 0, stream,
                       x, (unsigned int*)xbf, sq);
    hipLaunchKernelGGL(dist_kernel, dim3(32, 32), dim3(256), 0, stream,
                       xbf, sq, out);
    hipLaunchKernelGGL(loss_kernel, dim3(2048), dim3(256), 0, stream,
                       out, noise, y, meant, stdt, partials);
    hipLaunchKernelGGL(finalize_kernel, dim3(1), dim3(256), 0, stream,
                       partials, out);
}

// Round 6
// 161.828 us; speedup vs baseline: 1.7625x; 1.0035x over previous
//
#include <hip/hip_runtime.h>
#include <hip/hip_bf16.h>

#define B 4096
#define DFEAT 128
#define NCLS 512
#define NEG_INF_F (-1e30f)

typedef __attribute__((ext_vector_type(8))) short bf16x8;
typedef __attribute__((ext_vector_type(4))) float f32x4;

__device__ __forceinline__ unsigned short f2bf(float f) {
    unsigned int u = __float_as_uint(f);
    unsigned int r = (u + 0x7fffu + ((u >> 16) & 1u)) >> 16;
    return (unsigned short)r;
}

// online softmax-weighted accumulation: add one entry with given logit, value d
__device__ __forceinline__ void oupd(float logit, float d, float& m, float& sw, float& swd) {
    if (logit > m) {
        float e = __expf(m - logit);   // m==-1e30 -> e==0 -> resets cleanly
        sw  = fmaf(sw, e, 1.0f);
        swd = fmaf(swd, e, d);
        m = logit;
    } else {
        float e = __expf(logit - m);
        sw += e;
        swd = fmaf(e, d, swd);
    }
}

__device__ __forceinline__ void omerge(float& m, float& sw, float& swd,
                                       float m2, float sw2, float swd2) {
    float M = fmaxf(m, m2);
    float e1 = __expf(m - M);
    float e2 = __expf(m2 - M);
    sw  = sw * e1 + sw2 * e2;
    swd = swd * e1 + swd2 * e2;
    m = M;
}

// reference band logic for a strictly-upper negative pair
__device__ __forceinline__ void neg_update(float d, float mu, float sg, float nz, float st[12]) {
    float obs = fmaf(sg, nz, mu);
    float t1 = fmaf(-2.5f, sg, obs);
    if (d < t1) {
        oupd(10.0f * (t1 - d), d, st[0], st[1], st[2]);
    } else {
        float tm = fmaf(-1.5f, sg, obs);
        if (d < tm) {
            if (d > t1) oupd(5.0f * (tm - d), d, st[3], st[4], st[5]);
        } else {
            float th = fmaf(1.5f, sg, obs);
            if (d < th && d > tm) oupd(5.0f * (th - d), d, st[6], st[7], st[8]);
        }
    }
}

__device__ __forceinline__ void wave_reduce12(float st[12]) {
    #pragma unroll
    for (int off = 32; off; off >>= 1) {
        float o[12];
        #pragma unroll
        for (int k = 0; k < 12; ++k) o[k] = __shfl_down(st[k], off);
        omerge(st[0], st[1], st[2], o[0], o[1], o[2]);
        omerge(st[3], st[4], st[5], o[3], o[4], o[5]);
        omerge(st[6], st[7], st[8], o[6], o[7], o[8]);
        st[9] += o[9]; st[10] += o[10]; st[11] += o[11];
    }
}

// ---------------- kernel 1: x -> bf16 copy + row sum-of-squares ----------------
__global__ void prep_kernel(const float* __restrict__ x,
                            unsigned int* __restrict__ xbf_packed,
                            float* __restrict__ sq) {
    int row = blockIdx.x;
    int lane = threadIdx.x;  // 64
    float2 v = ((const float2*)(x + row * DFEAT))[lane];
    float ss = fmaf(v.x, v.x, v.y * v.y);
    unsigned int pk = ((unsigned int)f2bf(v.y) << 16) | (unsigned int)f2bf(v.x);
    xbf_packed[row * (DFEAT / 2) + lane] = pk;
    #pragma unroll
    for (int off = 32; off; off >>= 1) ss += __shfl_down(ss, off);
    if (lane == 0) sq[row] = ss;
}

// ---------------- kernel 2: pure GEMM -> dist write ----------------
__launch_bounds__(256)
__global__ void dist_kernel(const unsigned short* __restrict__ xbf,
                            const float* __restrict__ sq,
                            float* __restrict__ out) {
    const int bx = blockIdx.x;       // col tile
    const int by = blockIdx.y;       // row tile
    const int tid = threadIdx.x;
    const int wave = tid >> 6;
    const int lane = tid & 63;
    const int q = lane >> 4;         // 0..3
    const int l16 = lane & 15;
    const int row0 = by * 128 + (wave >> 1) * 64;
    const int col0 = bx * 128 + (wave & 1) * 64;

    f32x4 acc[4][4];
    #pragma unroll
    for (int r = 0; r < 4; ++r)
        #pragma unroll
        for (int c = 0; c < 4; ++c)
            acc[r][c] = (f32x4){0.f, 0.f, 0.f, 0.f};

    #pragma unroll
    for (int kk = 0; kk < 4; ++kk) {
        const int ko = kk * 32 + q * 8;
        bf16x8 afr[4], bfr[4];
        #pragma unroll
        for (int r = 0; r < 4; ++r)
            afr[r] = *(const bf16x8*)(xbf + (row0 + r * 16 + l16) * DFEAT + ko);
        #pragma unroll
        for (int c = 0; c < 4; ++c)
            bfr[c] = *(const bf16x8*)(xbf + (col0 + c * 16 + l16) * DFEAT + ko);
        #pragma unroll
        for (int r = 0; r < 4; ++r)
            #pragma unroll
            for (int c = 0; c < 4; ++c)
                acc[r][c] = __builtin_amdgcn_mfma_f32_16x16x32_bf16(afr[r], bfr[c], acc[r][c], 0, 0, 0);
    }

    float sqr[4][4];
    #pragma unroll
    for (int r = 0; r < 4; ++r)
        *(f32x4*)sqr[r] = *(const f32x4*)(sq + row0 + r * 16 + q * 4);
    int cols[4]; float sqc[4];
    #pragma unroll
    for (int c = 0; c < 4; ++c) {
        cols[c] = col0 + c * 16 + l16;
        sqc[c] = sq[cols[c]];
    }

    #pragma unroll
    for (int r = 0; r < 4; ++r) {
        #pragma unroll
        for (int t = 0; t < 4; ++t) {
            int base = (row0 + r * 16 + q * 4 + t) * B;
            float s = sqr[r][t];
            #pragma unroll
            for (int c = 0; c < 4; ++c)
                out[base + cols[c]] = fmaf(-2.0f, acc[r][c][t], s + sqc[c]);
        }
    }
}

// ---------------- kernel 3: streaming upper-triangle loss ----------------
// block b handles rows i=b and j=B-1-b (4095 elements total, balanced).
// positives for row r are exactly cols r+1..(r|7)  (<=7, scalar head);
// negatives are cols (r|7)+1..B-1 (8-aligned start -> float4 body, branch-free).
__device__ __forceinline__ void process_row(int row,
                                            const float* __restrict__ drow,
                                            const float* __restrict__ nrow,
                                            const int* __restrict__ y,
                                            const float* __restrict__ muS,
                                            const float* __restrict__ sgS,
                                            int tid, float st[12]) {
    const int ge = row | 7;
    const int npos = ge - row;         // 0..7
    if (tid < npos) {
        int col = row + 1 + tid;
        float d = drow[col], nz = nrow[col];
        int yc = y[col];
        float sg = sgS[yc];
        float obs = fmaf(sg, nz, muS[yc]);
        float tp = fmaf(2.0f, sg, obs);
        if (d > tp) { st[9] += d; st[10] = fmaf(d, d, st[10]); st[11] += 1.0f; }
    }
    for (int col = ge + 1 + tid * 4; col < B; col += 1024) {
        float4 d4 = *(const float4*)(drow + col);
        float4 n4 = *(const float4*)(nrow + col);
        int4  y4 = *(const int4*)(y + col);
        neg_update(d4.x, muS[y4.x], sgS[y4.x], n4.x, st);
        neg_update(d4.y, muS[y4.y], sgS[y4.y], n4.y, st);
        neg_update(d4.z, muS[y4.z], sgS[y4.z], n4.z, st);
        neg_update(d4.w, muS[y4.w], sgS[y4.w], n4.w, st);
    }
}

__launch_bounds__(256)
__global__ void loss_kernel(const float* __restrict__ dist,
                            const float* __restrict__ noise,
                            const int* __restrict__ y,
                            const float* __restrict__ meant,
                            const float* __restrict__ stdt,
                            float* __restrict__ partials) {
    const int b = blockIdx.x;       // 0..2047
    const int i = b;
    const int j = B - 1 - b;
    const int tid = threadIdx.x;
    const int lane = tid & 63, wave = tid >> 6;

    __shared__ float mu0[NCLS], sg0[NCLS], mu1[NCLS], sg1[NCLS];
    const int yi = y[i], yj = y[j];
    for (int c = tid * 4; c < NCLS; c += 1024) {
        *(float4*)(mu0 + c) = *(const float4*)(meant + yi * NCLS + c);
        *(float4*)(sg0 + c) = *(const float4*)(stdt  + yi * NCLS + c);
        *(float4*)(mu1 + c) = *(const float4*)(meant + yj * NCLS + c);
        *(float4*)(sg1 + c) = *(const float4*)(stdt  + yj * NCLS + c);
    }
    __syncthreads();

    // st: [0..2]=n1(m,sw,swd) [3..5]=n2 [6..8]=n3 [9..11]=(ps,ps2,cnt)
    float st[12];
    st[0] = st[3] = st[6] = NEG_INF_F;
    st[1] = st[2] = st[4] = st[5] = st[7] = st[8] = st[9] = st[10] = st[11] = 0.f;

    process_row(i, dist + (size_t)i * B, noise + (size_t)i * B, y, mu0, sg0, tid, st);
    process_row(j, dist + (size_t)j * B, noise + (size_t)j * B, y, mu1, sg1, tid, st);

    wave_reduce12(st);

    __shared__ float red[4][12];
    if (lane == 0) {
        #pragma unroll
        for (int k = 0; k < 12; ++k) red[wave][k] = st[k];
    }
    __syncthreads();
    if (tid == 0) {
        float r0[12];
        #pragma unroll
        for (int k = 0; k < 12; ++k) r0[k] = red[0][k];
        #pragma unroll
        for (int w = 1; w < 4; ++w) {
            omerge(r0[0], r0[1], r0[2], red[w][0], red[w][1], red[w][2]);
            omerge(r0[3], r0[4], r0[5], red[w][3], red[w][4], red[w][5]);
            omerge(r0[6], r0[7], r0[8], red[w][6], red[w][7], red[w][8]);
            r0[9] += red[w][9]; r0[10] += red[w][10]; r0[11] += red[w][11];
        }
        float* pp = partials + b * 12;
        #pragma unroll
        for (int k = 0; k < 12; ++k) pp[k] = r0[k];
    }
}

// ---------------- kernel 4: final reduction + loss ----------------
__global__ void finalize_kernel(const float* __restrict__ partials,
                                float* __restrict__ out) {
    int tid = threadIdx.x;  // 256
    int lane = tid & 63, wave = tid >> 6;
    float st[12];
    st[0] = st[3] = st[6] = NEG_INF_F;
    st[1] = st[2] = st[4] = st[5] = st[7] = st[8] = st[9] = st[10] = st[11] = 0.f;
    for (int p = tid; p < 2048; p += 256) {
        const float* pp = partials + p * 12;
        omerge(st[0], st[1], st[2], pp[0], pp[1], pp[2]);
        omerge(st[3], st[4], st[5], pp[3], pp[4], pp[5]);
        omerge(st[6], st[7], st[8], pp[6], pp[7], pp[8]);
        st[9] += pp[9]; st[10] += pp[10]; st[11] += pp[11];
    }
    wave_reduce12(st);
    __shared__ float red[4][12];
    if (lane == 0) {
        #pragma unroll
        for (int k = 0; k < 12; ++k) red[wave][k] = st[k];
    }
    __syncthreads();
    if (tid == 0) {
        float r0[12];
        #pragma unroll
        for (int k = 0; k < 12; ++k) r0[k] = red[0][k];
        #pragma unroll
        for (int w = 1; w < 4; ++w) {
            omerge(r0[0], r0[1], r0[2], red[w][0], red[w][1], red[w][2]);
            omerge(r0[3], r0[4], r0[5], red[w][3], red[w][4], red[w][5]);
            omerge(r0[6], r0[7], r0[8], red[w][6], red[w][7], red[w][8]);
            r0[9] += red[w][9]; r0[10] += red[w][10]; r0[11] += red[w][11];
        }
        float ln1 = (r0[1] > 0.f) ? -(r0[2] / r0[1]) : -0.0001f;
        float ln2 = (r0[4] > 0.f) ? -(r0[5] / r0[4]) : -0.0001f;
        float ln3 = (r0[7] > 0.f) ? -(r0[8] / r0[7]) : -0.0001f;
        float lp  = (r0[11] > 0.f) ? (r0[10] / ((r0[9] != 0.f) ? r0[9] : 1.f)) : 0.0001f;
        out[(size_t)B * B] = 1.0f + 0.25f * (ln1 + ln2 + ln3 + lp);
    }
}

extern "C" void kernel_launch(void* const* d_in, const int* in_sizes, int n_in,
                              void* d_out, int out_size, void* d_ws, size_t ws_size,
                              hipStream_t stream) {
    const float* x     = (const float*)d_in[0];
    const int*   y     = (const int*)d_in[1];
    const float* meant = (const float*)d_in[2];
    const float* stdt  = (const float*)d_in[3];
    const float* noise = (const float*)d_in[4];
    float* out = (float*)d_out;
    char* ws = (char*)d_ws;
    unsigned short* xbf = (unsigned short*)ws;            // 1 MiB
    float* sq           = (float*)(ws + 1048576);         // 16 KiB
    float* partials     = (float*)(ws + 1064960);         // 2048*12*4 = 96 KiB

    hipLaunchKernelGGL(prep_kernel, dim3(B), dim3(64), 0, stream,
                       x, (unsigned int*)xbf, sq);
    hipLaunchKernelGGL(dist_kernel, dim3(32, 32), dim3(256), 0, stream,
                       xbf, sq, out);
    hipLaunchKernelGGL(loss_kernel, dim3(2048), dim3(256), 0, stream,
                       out, noise, y, meant, stdt, partials);
    hipLaunchKernelGGL(finalize_kernel, dim3(1), dim3(256), 0, stream,
                       partials, out);
}